// Round 1
// baseline (1037.034 us; speedup 1.0000x reference)
//
#include <hip/hip_runtime.h>
#include <math.h>

#define L_SEQ 200
#define Q_DIM 128
#define H_DIM 128

// One block per batch row b. 256 threads = 4 waves.
// Thread t: lane32 = t&31 owns h-slice [lane32*4, lane32*4+4);
//           lgroup = t>>5 owns l-rows {i*8 + lgroup, i=0..24}.
// Entire 200x128 fp32 hist row lives in registers (25 x float4 / thread)
// so HBM reads it exactly once (memory-bound kernel, floor ~134us).
__global__ __launch_bounds__(256, 3) void attn_pool(
    const float* __restrict__ query,   // [B, 128]
    const float* __restrict__ hist,    // [B, 200, 128]
    const int*   __restrict__ lens,    // [B]
    const float* __restrict__ W,       // [128, 128]
    float* __restrict__ out)           // [B, 128]
{
    const int b = blockIdx.x;
    const int t = threadIdx.x;
    const int lane32 = t & 31;
    const int lgroup = t >> 5;   // 0..7
    const int wid    = t >> 6;   // 0..3

    __shared__ float s_q[Q_DIM];
    __shared__ float s_qw[H_DIM];
    __shared__ float s_part[8 * H_DIM];
    __shared__ float s_logits[L_SEQ];
    __shared__ float s_red[4];
    __shared__ float s_scalar[2];

    // ---------- phase 0: qw[h] = sum_q query[b,q] * W[q,h] ----------
    if (t < Q_DIM) s_q[t] = query[(size_t)b * Q_DIM + t];
    __syncthreads();
    {
        const int h  = t & 127;
        const int qh = t >> 7;       // 0 or 1: each half handles 64 q's
        float acc = 0.f;
        #pragma unroll 8
        for (int i = 0; i < 64; ++i) {
            const int q = qh * 64 + i;
            acc = fmaf(s_q[q], W[q * H_DIM + h], acc);   // coalesced W read (L2-hot)
        }
        s_part[t] = acc;
    }
    __syncthreads();
    if (t < H_DIM) s_qw[t] = s_part[t] + s_part[t + 128];
    __syncthreads();

    const float4 qw4 = reinterpret_cast<const float4*>(s_qw)[lane32];

    // ---------- load hist row into registers (coalesced float4) ----------
    const float* hrow = hist + (size_t)b * (L_SEQ * H_DIM);
    float4 r[25];
    #pragma unroll
    for (int i = 0; i < 25; ++i) {
        const int l = i * 8 + lgroup;
        r[i] = reinterpret_cast<const float4*>(hrow + l * H_DIM)[lane32];
    }

    // ---------- pass 1: logits[l] = qw . hist[l,:] ----------
    #pragma unroll
    for (int i = 0; i < 25; ++i) {
        float p = qw4.x * r[i].x + qw4.y * r[i].y + qw4.z * r[i].z + qw4.w * r[i].w;
        p += __shfl_down(p, 16, 32);
        p += __shfl_down(p, 8, 32);
        p += __shfl_down(p, 4, 32);
        p += __shfl_down(p, 2, 32);
        p += __shfl_down(p, 1, 32);
        if (lane32 == 0) s_logits[i * 8 + lgroup] = p;
    }
    __syncthreads();

    // ---------- mask (faithful: valid prefix -> 1e-9) + softmax ----------
    const int len = lens[b];
    float x = -3.0e38f;
    if (t < L_SEQ) {
        const float v = s_logits[t];
        x = (t < len) ? 1e-9f : v;
    }
    // block max
    float m = x;
    m = fmaxf(m, __shfl_down(m, 32));
    m = fmaxf(m, __shfl_down(m, 16));
    m = fmaxf(m, __shfl_down(m, 8));
    m = fmaxf(m, __shfl_down(m, 4));
    m = fmaxf(m, __shfl_down(m, 2));
    m = fmaxf(m, __shfl_down(m, 1));
    if ((t & 63) == 0) s_red[wid] = m;
    __syncthreads();
    if (t == 0)
        s_scalar[0] = fmaxf(fmaxf(s_red[0], s_red[1]), fmaxf(s_red[2], s_red[3]));
    __syncthreads();
    const float gmax = s_scalar[0];

    float e = 0.f;
    if (t < L_SEQ) {
        e = __expf(x - gmax);
        s_logits[t] = e;     // store numerator
    }
    float ssum = e;
    ssum += __shfl_down(ssum, 32);
    ssum += __shfl_down(ssum, 16);
    ssum += __shfl_down(ssum, 8);
    ssum += __shfl_down(ssum, 4);
    ssum += __shfl_down(ssum, 2);
    ssum += __shfl_down(ssum, 1);
    if ((t & 63) == 0) s_red[wid] = ssum;
    __syncthreads();
    if (t == 0) s_scalar[1] = s_red[0] + s_red[1] + s_red[2] + s_red[3];
    __syncthreads();
    const float inv = 1.0f / s_scalar[1];

    // ---------- pass 2: out[h] = sum_l score[l] * hist[l,h] ----------
    float4 acc = make_float4(0.f, 0.f, 0.f, 0.f);
    #pragma unroll
    for (int i = 0; i < 25; ++i) {
        const float s = s_logits[i * 8 + lgroup] * inv;   // LDS broadcast
        acc.x = fmaf(s, r[i].x, acc.x);
        acc.y = fmaf(s, r[i].y, acc.y);
        acc.z = fmaf(s, r[i].z, acc.z);
        acc.w = fmaf(s, r[i].w, acc.w);
    }
    reinterpret_cast<float4*>(s_part)[lgroup * 32 + lane32] = acc;
    __syncthreads();
    if (t < H_DIM) {
        float v = 0.f;
        #pragma unroll
        for (int g = 0; g < 8; ++g) v += s_part[g * H_DIM + t];
        out[(size_t)b * H_DIM + t] = v;
    }
}

extern "C" void kernel_launch(void* const* d_in, const int* in_sizes, int n_in,
                              void* d_out, int out_size, void* d_ws, size_t ws_size,
                              hipStream_t stream) {
    const float* query = (const float*)d_in[0];   // [B, 128]
    const float* hist  = (const float*)d_in[1];   // [B, 200, 128]
    const int*   lens  = (const int*)d_in[2];     // [B]
    const float* W     = (const float*)d_in[3];   // [128, 128]
    float* out = (float*)d_out;                   // [B, 128]

    const int B = in_sizes[2];                    // 8192
    attn_pool<<<dim3(B), dim3(256), 0, stream>>>(query, hist, lens, W, out);
}